// Round 1
// baseline (202.019 us; speedup 1.0000x reference)
//
#include <hip/hip_runtime.h>

// Problem constants (fixed by setup_inputs)
#define Bdim 32
#define Ndim 64
#define Tdim 40
#define Adim 6
#define Zdim 64
#define Cdim 3

// One wave (64 lanes) per (b,n,t). lane == c index into Z.
// logits[b,n,t,a] = dot(df[b,n,t,a,:], z[b,n,:]) + base_u[a] - feas_mean(base_u)
// (frenet/projection term cancels exactly in u - u_mean: it is constant over (t,a))
__global__ __launch_bounds__(256) void mpd_logits_kernel(
    const float* __restrict__ z,     // (B,N,Z)
    const float* __restrict__ df,    // (B,N,T,A,Z)
    const float* __restrict__ ctx,   // (B,N,T,A,C)
    const int*   __restrict__ feas,  // (B,N,T,A)
    const float* __restrict__ w,     // (C,)
    const float* __restrict__ b0,    // (1,)
    float*       __restrict__ out)   // (B,N,T,A)
{
    const int lane = threadIdx.x & 63;
    const int wave = (blockIdx.x * blockDim.x + threadIdx.x) >> 6; // (b*N+n)*T + t
    const int total = Bdim * Ndim * Tdim;
    if (wave >= total) return;

    const int bn = wave / Tdim; // b*N + n

    // Per-lane z element for this (b,n); reused across all 6 actions.
    const float zc = z[bn * Zdim + lane];

    // Dot products: 6 coalesced 256B rows, full-wave butterfly reduce each.
    const long long dfbase = (long long)wave * (Adim * Zdim);
    float dot[Adim];
#pragma unroll
    for (int a = 0; a < Adim; ++a) {
        float p = df[dfbase + a * Zdim + lane] * zc;
#pragma unroll
        for (int off = 32; off >= 1; off >>= 1)
            p += __shfl_xor(p, off, 64);
        dot[a] = p; // all lanes hold the full sum
    }

    // Lanes 0..5: base_u and feasibility for action a = lane.
    const float w0 = w[0], w1 = w[1], w2 = w[2], bb = b0[0];
    float base = 0.0f;
    bool  fa   = false;
    if (lane < Adim) {
        const float* cp = ctx + (long long)wave * (Adim * Cdim) + lane * Cdim;
        base = cp[0] * w0 + cp[1] * w1 + cp[2] * w2 + bb;
        fa = (feas[wave * Adim + lane] != 0);
    }

    // any(feasible) over this (b,n,t); if none, treat all as feasible.
    const bool anyfa = (__ballot(fa) != 0ULL);
    const float fv = (lane < Adim) ? (anyfa ? (fa ? 1.0f : 0.0f) : 1.0f) : 0.0f;

    // Octet xor-reduce (offsets 4,2,1): lanes 0..7 mix only among themselves,
    // lanes 6,7 contribute zeros.
    float bsum = base * fv;
    float csum = fv;
#pragma unroll
    for (int off = 4; off >= 1; off >>= 1) {
        bsum += __shfl_xor(bsum, off, 64);
        csum += __shfl_xor(csum, off, 64);
    }
    const float mean = bsum / fmaxf(csum, 1e-6f);

    if (lane < Adim) {
        // Select dot[lane] (small cndmask chain; no scratch spill).
        float d = dot[0];
        if (lane == 1) d = dot[1];
        else if (lane == 2) d = dot[2];
        else if (lane == 3) d = dot[3];
        else if (lane == 4) d = dot[4];
        else if (lane == 5) d = dot[5];
        out[wave * Adim + lane] = d + base - mean;
    }
}

extern "C" void kernel_launch(void* const* d_in, const int* in_sizes, int n_in,
                              void* d_out, int out_size, void* d_ws, size_t ws_size,
                              hipStream_t stream) {
    // Input order: map_polylines(0), idx(1), pts(2), z(3), decision_features(4),
    //              ctx_features(5), feasible_actions(6), u_ctx_w(7), u_ctx_b(8)
    const float* z    = (const float*)d_in[3];
    const float* df   = (const float*)d_in[4];
    const float* ctx  = (const float*)d_in[5];
    const int*   feas = (const int*)  d_in[6];
    const float* w    = (const float*)d_in[7];
    const float* b0   = (const float*)d_in[8];
    float* out = (float*)d_out;

    const int totalWaves = Bdim * Ndim * Tdim;      // 81920
    const int block = 256;                           // 4 waves/block
    const int grid = (totalWaves * 64 + block - 1) / block; // 20480

    mpd_logits_kernel<<<grid, block, 0, stream>>>(z, df, ctx, feas, w, b0, out);
}